// Round 16
// baseline (40.422 us; speedup 1.0000x reference)
//
#include <hip/hip_runtime.h>

#define NQ 12
#define NSTATE (1 << NQ)   // 4096 amps
#define TPB 256            // 16 float2 amps/thread; ONE batch element per block

// One element per block (32 KB LDS exactly) to raise co-resident blocks/CU.
// R15-verified algebra: 3 LDS passes per layer (4 qubits each); layer 1
// folded into init (product state, its Gray perm absorbed via j = g(i));
// per-layer CNOT Gray perm new[i]=old[g(i)], g(i)=i^(i>>1), applied as a
// g^-1 scatter at pass-C store; layer 6 amputated to gate 60 only.
// LDS phys = swz(i) = i ^ ((i>>4)&0xF); slots are float2 (b64).
// Gate constants in lane slots, broadcast via v_readlane.

__device__ __forceinline__ float RL(float v, int idx) {
    return __int_as_float(__builtin_amdgcn_readlane(__float_as_int(v), idx));
}

// Rot(phi,theta,omega): u00=(A,-B) u01=(-C,-D) u10=(C,-D) u11=(A,B)
__device__ __forceinline__ void bf1(float2& s0, float2& s1,
                                    float A, float B, float C, float D) {
    float n0x = fmaf(A, s0.x, fmaf( B, s0.y, fmaf(-C, s1.x,  D * s1.y)));
    float n0y = fmaf(A, s0.y, fmaf(-B, s0.x, fmaf(-C, s1.y, -D * s1.x)));
    float n1x = fmaf(C, s0.x, fmaf( D, s0.y, fmaf( A, s1.x, -B * s1.y)));
    float n1y = fmaf(C, s0.y, fmaf(-D, s0.x, fmaf( A, s1.y,  B * s1.x)));
    s0 = make_float2(n0x, n0y); s1 = make_float2(n1x, n1y);
}

#define BF(i,j) bf1(a##i, a##j, A, B, C, D)
#define PK0 BF(0,1); BF(2,3); BF(4,5); BF(6,7); \
            BF(8,9); BF(10,11); BF(12,13); BF(14,15);
#define PK1 BF(0,2); BF(1,3); BF(4,6); BF(5,7); \
            BF(8,10); BF(9,11); BF(12,14); BF(13,15);
#define PK2 BF(0,4); BF(1,5); BF(2,6); BF(3,7); \
            BF(8,12); BF(9,13); BF(10,14); BF(11,15);
#define PK3 BF(0,8); BF(1,9); BF(2,10); BF(3,11); \
            BF(4,12); BF(5,13); BF(6,14); BF(7,15);
#define GATE(qq, P) { const int gi = gb + (qq); \
    const float A = RL(gA, gi), B = RL(gB, gi), \
                C = RL(gC, gi), D = RL(gD, gi); P }

#define LDS2(off) (*(float2*)((char*)st + (off)))
#define LD1(r, ADR) a##r = LDS2(ADR(r));
#define ST1(r, ADR) LDS2(ADR(r)) = a##r;
#define LD16(ADR) { LD1(0,ADR) LD1(1,ADR) LD1(2,ADR) LD1(3,ADR) \
                    LD1(4,ADR) LD1(5,ADR) LD1(6,ADR) LD1(7,ADR) \
                    LD1(8,ADR) LD1(9,ADR) LD1(10,ADR) LD1(11,ADR) \
                    LD1(12,ADR) LD1(13,ADR) LD1(14,ADR) LD1(15,ADR) }
#define ST16(ADR) { ST1(0,ADR) ST1(1,ADR) ST1(2,ADR) ST1(3,ADR) \
                    ST1(4,ADR) ST1(5,ADR) ST1(6,ADR) ST1(7,ADR) \
                    ST1(8,ADR) ST1(9,ADR) ST1(10,ADR) ST1(11,ADR) \
                    ST1(12,ADR) ST1(13,ADR) ST1(14,ADR) ST1(15,ADR) }

// Byte-address tilings (t = 8-bit thread, r = 4-bit reg, slot byte = idx<<3):
// A: i=(r<<8)|t  -> phys = (r<<8)+(t^(t>>4))          (offset-immediate)
// B: i=t[7:4]<<8|r<<4|t[3:0] -> phys = ptB ^ (r<<4) ^ r
// C: i=(t<<4)|r  -> phys = (t<<4)^(t&0xF)^r
// C-scatter: store i at swz(g^-1(i)) = ptCS ^ ginv4(r)
#define ADRA(r)   (ptAb + ((r) << 11))
#define ADRB(r)   (ptBb ^ (((r) << 7) ^ ((r) << 3)))
#define ADRC(r)   (ptCb ^ ((r) << 3))
#define GINV4(r)  ((r) ^ ((r) >> 1) ^ ((r) >> 2) ^ ((r) >> 3))
#define ADRCS(r)  (ptCSb ^ (GINV4(r) << 3))

// ---- init helpers (post-layer-1 product state; R15-verified algebra) ----
#define CM(n, xr, xi, yr, yi) \
    const float n##r = fmaf(xr, yr, -(xi) * (yi)); \
    const float n##i = fmaf(xr, yi,  (xi) * (yr));
#define GCONST(q) const float A##q = RL(gA, q), B##q = RL(gB, q), \
                              C##q = RL(gC, q), D##q = RL(gD, q);
// v_q = Rot_q * (cos, -i sin)
#define VQDEF(q) \
    const float v##q##0r = fmaf(A##q, c##q, -(D##q) * s##q); \
    const float v##q##0i = fmaf(-(B##q), c##q,  (C##q) * s##q); \
    const float v##q##1r = fmaf(C##q, c##q,  (B##q) * s##q); \
    const float v##q##1i = fmaf(-(D##q), c##q, -(A##q) * s##q);
#define WSEL(q, b) \
    const float w##q##r = (tj & (1 << (b))) ? v##q##1r : v##q##0r; \
    const float w##q##i = (tj & (1 << (b))) ? v##q##1i : v##q##0i;
#define SETAMP(g, rp, mm) \
    a##g = make_float2(fmaf(mm##r, Q##rp##r, -(mm##i) * Q##rp##i), \
                       fmaf(mm##r, Q##rp##i,  (mm##i) * Q##rp##r));

__global__ __launch_bounds__(TPB) void qsim_kernel(
    const float* __restrict__ x,      // (B, 12)
    const float* __restrict__ w,      // (6, 12, 3)
    const float* __restrict__ hw,     // (2, 1)
    const float* __restrict__ hb,     // (2,)
    float* __restrict__ out)          // (B, 2)
{
    __shared__ float2 st[NSTATE];     // exactly 32 KB

    const int t    = threadIdx.x;     // 8 bits
    const int lane = t & 63;
    const int e    = blockIdx.x;      // one element per block

    // ---- prologue: gate-constant quads into lane slots (gates 0..60 used) ----
    float gA, gB, gC, gD;
    {
        const float* wl = w + lane * 3;
        float phi = wl[0], th = wl[1], om = wl[2];
        float c, s, ca, sa, cb, sb;
        __sincosf(0.5f * th, &s, &c);
        __sincosf(0.5f * (phi + om), &sa, &ca);
        __sincosf(0.5f * (phi - om), &sb, &cb);
        gA = c * ca; gB = c * sa; gC = s * cb; gD = s * sb;
    }

    // ---- loop-invariant BYTE address bases ----
    const int ptAb  = (t ^ (t >> 4)) << 3;
    const int ptBb  = ((((t & 0xF0) << 4) | (t & 0x0F))) << 3;
    const int ptCb  = (((t << 4) ^ (t & 0x0F))) << 3;
    int gv = t << 4;                  // g^-1 = suffix parity (GF(2)-linear)
    gv ^= gv >> 1; gv ^= gv >> 2; gv ^= gv >> 4; gv ^= gv >> 8; gv &= 0xFFF;
    const int ptCSb = (gv ^ ((gv >> 4) & 0xF)) << 3;

    float2 a0, a1, a2, a3, a4, a5, a6, a7,
           a8, a9, a10, a11, a12, a13, a14, a15;

    #pragma unroll 1
    for (int k = 0; k < 4; ++k) {     // layers 2..5 (gates 12..59)
        const int gb = (k + 1) * 12;

        // ---- Pass A: state bits 11..8 (qubits 0..3) ----
        if (k == 0) {
            // init = post-layer-1 product state at i=(r<<8)|t, j = g(i):
            //   j11..9 = g4(r)>>1, j8 = r0^r1, j7 = t7^r0, j6..0 = tj bits 6..0
            const int tj = t ^ (t >> 1);
            const int t7 = (t >> 7) & 1;
            GCONST(0)  GCONST(1)  GCONST(2)  GCONST(3)
            GCONST(4)  GCONST(5)  GCONST(6)  GCONST(7)
            GCONST(8)  GCONST(9)  GCONST(10) GCONST(11)
            const float* xe = x + e * NQ;
            float c0,s0,c1,s1,c2,s2,c3,s3,c4,s4,c5,s5;
            float c6,s6,c7,s7,c8,s8,c9,s9,c10,s10,c11,s11;
            #define EMB(q) __sincosf(0.5f * xe[q], &s##q, &c##q);
            EMB(0) EMB(1) EMB(2) EMB(3) EMB(4)  EMB(5)
            EMB(6) EMB(7) EMB(8) EMB(9) EMB(10) EMB(11)
            #undef EMB
            // qubits 5..11 from tj bits 6..0
            VQDEF(5)  WSEL(5,6)  VQDEF(6)  WSEL(6,5)
            VQDEF(7)  WSEL(7,4)  VQDEF(8)  WSEL(8,3)
            VQDEF(9)  WSEL(9,2)  VQDEF(10) WSEL(10,1)
            VQDEF(11) WSEL(11,0)
            CM(m56, w5r, w5i, w6r, w6i)   CM(m78, w7r, w7i, w8r, w8i)
            CM(m9A, w9r, w9i, w10r, w10i)
            CM(mP, m56r, m56i, m78r, m78i) CM(mQ, m9Ar, m9Ai, w11r, w11i)
            CM(mL, mPr, mPi, mQr, mQi)     // product over qubits 5..11
            // qubit 4: j7 = t7 ^ r0
            VQDEF(4)
            const float w4ar = t7 ? v41r : v40r, w4ai = t7 ? v41i : v40i;
            const float w4br = t7 ? v40r : v41r, w4bi = t7 ? v40i : v41i;
            CM(Pa, mLr, mLi, w4ar, w4ai)   CM(Pb, mLr, mLi, w4br, w4bi)
            // qubit 3: j8 = r0^r1
            VQDEF(3)
            CM(T00, Par, Pai, v30r, v30i)  CM(T01, Par, Pai, v31r, v31i)
            CM(T10, Pbr, Pbi, v31r, v31i)  CM(T11, Pbr, Pbi, v30r, v30i)
            // qubits 0..2: Q[z], z = g4(r)>>1 (bit2=q0, bit1=q1, bit0=q2)
            VQDEF(0) VQDEF(1) VQDEF(2)
            CM(H0, v00r, v00i, v10r, v10i) CM(H1, v00r, v00i, v11r, v11i)
            CM(H2, v01r, v01i, v10r, v10i) CM(H3, v01r, v01i, v11r, v11i)
            CM(Q0, H0r, H0i, v20r, v20i)   CM(Q1, H0r, H0i, v21r, v21i)
            CM(Q2, H1r, H1i, v20r, v20i)   CM(Q3, H1r, H1i, v21r, v21i)
            CM(Q4, H2r, H2i, v20r, v20i)   CM(Q5, H2r, H2i, v21r, v21i)
            CM(Q6, H3r, H3i, v20r, v20i)   CM(Q7, H3r, H3i, v21r, v21i)
            SETAMP(0,0,T00)  SETAMP(1,0,T10)
            SETAMP(2,1,T01)  SETAMP(3,1,T11)
            SETAMP(4,3,T00)  SETAMP(5,3,T10)
            SETAMP(6,2,T01)  SETAMP(7,2,T11)
            SETAMP(8,6,T00)  SETAMP(9,6,T10)
            SETAMP(10,7,T01) SETAMP(11,7,T11)
            SETAMP(12,5,T00) SETAMP(13,5,T10)
            SETAMP(14,4,T01) SETAMP(15,4,T11)
        } else {
            LD16(ADRA)
        }
        // reg bit k <-> state bit 8+k <-> qubit 3-k
        GATE(3, PK0) GATE(2, PK1) GATE(1, PK2) GATE(0, PK3)
        ST16(ADRA)
        __syncthreads();

        // ---- Pass B: state bits 7..4 (qubits 4..7) ----
        LD16(ADRB)
        GATE(7, PK0) GATE(6, PK1) GATE(5, PK2) GATE(4, PK3)
        ST16(ADRB)
        __syncthreads();

        // ---- Pass C: state bits 3..0 (qubits 8..11) + Gray scatter ----
        LD16(ADRC)
        GATE(11, PK0) GATE(10, PK1) GATE(9, PK2) GATE(8, PK3)
        __syncthreads();              // all pass-C reads done before scatter
        ST16(ADRCS)                   // Gray perm via g^-1 scatter
        __syncthreads();
    }

    // ---- final layer (w[5]): only gate 60 (qubit 0 = state bit 11 = reg
    //      bit 3) survives inside <Z_0>; the rest commutes out. ----
    LD16(ADRA)
    {
        const float A = RL(gA, 60), B = RL(gB, 60),
                    C = RL(gC, 60), D = RL(gD, 60);
        bf1(a0, a8,  A, B, C, D); bf1(a1, a9,  A, B, C, D);
        bf1(a2, a10, A, B, C, D); bf1(a3, a11, A, B, C, D);
        bf1(a4, a12, A, B, C, D); bf1(a5, a13, A, B, C, D);
        bf1(a6, a14, A, B, C, D); bf1(a7, a15, A, B, C, D);
    }

    // ---- <Z_0> = sum(|r<8|^2) - sum(|r>=8|^2) ----
    float za = 0.0f;
    za += a0.x*a0.x + a0.y*a0.y;    za += a1.x*a1.x + a1.y*a1.y;
    za += a2.x*a2.x + a2.y*a2.y;    za += a3.x*a3.x + a3.y*a3.y;
    za += a4.x*a4.x + a4.y*a4.y;    za += a5.x*a5.x + a5.y*a5.y;
    za += a6.x*a6.x + a6.y*a6.y;    za += a7.x*a7.x + a7.y*a7.y;
    za -= a8.x*a8.x + a8.y*a8.y;    za -= a9.x*a9.x + a9.y*a9.y;
    za -= a10.x*a10.x + a10.y*a10.y; za -= a11.x*a11.x + a11.y*a11.y;
    za -= a12.x*a12.x + a12.y*a12.y; za -= a13.x*a13.x + a13.y*a13.y;
    za -= a14.x*a14.x + a14.y*a14.y; za -= a15.x*a15.x + a15.y*a15.y;

    #pragma unroll
    for (int off = 32; off >= 1; off >>= 1)
        za += __shfl_down(za, off);

    __syncthreads();                  // all final-pass reads done before reuse
    float* red = (float*)st;
    if (lane == 0) red[t >> 6] = za;
    __syncthreads();

    if (t == 0) {
        float zt = red[0] + red[1] + red[2] + red[3];
        out[2 * e + 0] = zt * hw[0] + hb[0];
        out[2 * e + 1] = zt * hw[1] + hb[1];
    }
}

extern "C" void kernel_launch(void* const* d_in, const int* in_sizes, int n_in,
                              void* d_out, int out_size, void* d_ws, size_t ws_size,
                              hipStream_t stream) {
    const float* x  = (const float*)d_in[0];
    const float* w  = (const float*)d_in[1];
    const float* hw = (const float*)d_in[2];
    const float* hb = (const float*)d_in[3];
    float* out = (float*)d_out;
    const int B = in_sizes[0] / NQ;   // 1024
    qsim_kernel<<<B, TPB, 0, stream>>>(x, w, hw, hb, out);
}

// Round 17
// 39.332 us; speedup vs baseline: 1.0277x; 1.0277x over previous
//
#include <hip/hip_runtime.h>

#define NQ 12
#define NSTATE (1 << NQ)   // 4096 amps per batch element
#define TPB 256            // 16 f4 slots/thread; TWO batch elements per slot

// R15 (verified, 39.6us) with ONE change: pass-C's read/write hazard barrier
// hoisted to directly after LD16 (it guards reads-before-overwrites only),
// removing the gate phase from the barrier-serialized window.
// Structure: 3 LDS passes/layer (4 qubits each); layer 1 folded into init;
// per-layer CNOT Gray perm new[i]=old[g(i)], g(i)=i^(i>>1), as g^-1 scatter
// at pass-C store; layer 6 amputated to gate 60. f4 slot = (reA,imA,reB,imB);
// LDS phys = swz(i) = i^((i>>4)&0xF); gate constants via v_readlane.

typedef float f4 __attribute__((ext_vector_type(4)));

struct A2 { float ar, ai, br, bi; };

__device__ __forceinline__ float RL(float v, int idx) {
    return __int_as_float(__builtin_amdgcn_readlane(__float_as_int(v), idx));
}

// Rot(phi,theta,omega): u00=(A,-B) u01=(-C,-D) u10=(C,-D) u11=(A,B)
__device__ __forceinline__ void bf2(A2& s0, A2& s1,
                                    float A, float B, float C, float D) {
    float n0r, n0i, n1r, n1i;
    n0r = fmaf(A, s0.ar, fmaf( B, s0.ai, fmaf(-C, s1.ar,  D * s1.ai)));
    n0i = fmaf(A, s0.ai, fmaf(-B, s0.ar, fmaf(-C, s1.ai, -D * s1.ar)));
    n1r = fmaf(C, s0.ar, fmaf( D, s0.ai, fmaf( A, s1.ar, -B * s1.ai)));
    n1i = fmaf(C, s0.ai, fmaf(-D, s0.ar, fmaf( A, s1.ai,  B * s1.ar)));
    s0.ar = n0r; s0.ai = n0i; s1.ar = n1r; s1.ai = n1i;
    n0r = fmaf(A, s0.br, fmaf( B, s0.bi, fmaf(-C, s1.br,  D * s1.bi)));
    n0i = fmaf(A, s0.bi, fmaf(-B, s0.br, fmaf(-C, s1.bi, -D * s1.br)));
    n1r = fmaf(C, s0.br, fmaf( D, s0.bi, fmaf( A, s1.br, -B * s1.bi)));
    n1i = fmaf(C, s0.bi, fmaf(-D, s0.br, fmaf( A, s1.bi,  B * s1.br)));
    s0.br = n0r; s0.bi = n0i; s1.br = n1r; s1.bi = n1i;
}

#define BF(i,j) bf2(a##i, a##j, A, B, C, D)
#define PK0 BF(0,1); BF(2,3); BF(4,5); BF(6,7); \
            BF(8,9); BF(10,11); BF(12,13); BF(14,15);
#define PK1 BF(0,2); BF(1,3); BF(4,6); BF(5,7); \
            BF(8,10); BF(9,11); BF(12,14); BF(13,15);
#define PK2 BF(0,4); BF(1,5); BF(2,6); BF(3,7); \
            BF(8,12); BF(9,13); BF(10,14); BF(11,15);
#define PK3 BF(0,8); BF(1,9); BF(2,10); BF(3,11); \
            BF(4,12); BF(5,13); BF(6,14); BF(7,15);
#define GATE(qq, P) { const int gi = gb + (qq); \
    const float A = RL(gA, gi), B = RL(gB, gi), \
                C = RL(gC, gi), D = RL(gD, gi); P }

#define LDS4(off) (*(f4*)((char*)st + (off)))
#define LD1(r, ADR) { f4 v = LDS4(ADR(r)); \
    a##r.ar = v.x; a##r.ai = v.y; a##r.br = v.z; a##r.bi = v.w; }
#define ST1(r, ADR) { f4 v = {a##r.ar, a##r.ai, a##r.br, a##r.bi}; \
    LDS4(ADR(r)) = v; }
#define LD16(ADR) { LD1(0,ADR) LD1(1,ADR) LD1(2,ADR) LD1(3,ADR) \
                    LD1(4,ADR) LD1(5,ADR) LD1(6,ADR) LD1(7,ADR) \
                    LD1(8,ADR) LD1(9,ADR) LD1(10,ADR) LD1(11,ADR) \
                    LD1(12,ADR) LD1(13,ADR) LD1(14,ADR) LD1(15,ADR) }
#define ST16(ADR) { ST1(0,ADR) ST1(1,ADR) ST1(2,ADR) ST1(3,ADR) \
                    ST1(4,ADR) ST1(5,ADR) ST1(6,ADR) ST1(7,ADR) \
                    ST1(8,ADR) ST1(9,ADR) ST1(10,ADR) ST1(11,ADR) \
                    ST1(12,ADR) ST1(13,ADR) ST1(14,ADR) ST1(15,ADR) }

// Byte-address tilings (t = 8-bit thread, r = 4-bit reg, slot byte = idx<<4):
// A: i=(r<<8)|t  -> phys = (r<<8)+(t^(t>>4))          (offset-immediate)
// B: i=t[7:4]<<8|r<<4|t[3:0] -> phys = ptB ^ (r<<4) ^ r
// C: i=(t<<4)|r  -> phys = (t<<4)+((t&0xF)^r)
// C-scatter: store i at swz(g^-1(i)) = ptCS ^ ginv4(r)
#define ADRA(r)   (ptAb + ((r) << 12))
#define ADRB(r)   (ptBb ^ (((r) << 8) ^ ((r) << 4)))
#define ADRC(r)   (ptCb ^ ((r) << 4))
#define GINV4(r)  ((r) ^ ((r) >> 1) ^ ((r) >> 2) ^ ((r) >> 3))
#define ADRCS(r)  (ptCSb ^ (GINV4(r) << 4))

// ---- init helpers (post-layer-1 product state; R12/R15-verified algebra) ----
#define CM(n, xr, xi, yr, yi) \
    const float n##r = fmaf(xr, yr, -(xi) * (yi)); \
    const float n##i = fmaf(xr, yi,  (xi) * (yr));
#define GCONST(q) const float A##q = RL(gA, q), B##q = RL(gB, q), \
                              C##q = RL(gC, q), D##q = RL(gD, q);
// v_q = Rot_q * (cos, -i sin)
#define VQDEF(q) \
    const float v##q##0r = fmaf(A##q, c##q, -(D##q) * s##q); \
    const float v##q##0i = fmaf(-(B##q), c##q,  (C##q) * s##q); \
    const float v##q##1r = fmaf(C##q, c##q,  (B##q) * s##q); \
    const float v##q##1i = fmaf(-(D##q), c##q, -(A##q) * s##q);
#define WSEL(q, b) \
    const float w##q##r = (tj & (1 << (b))) ? v##q##1r : v##q##0r; \
    const float w##q##i = (tj & (1 << (b))) ? v##q##1i : v##q##0i;
#define SETAMP(g, rp, mm, RE, IM) \
    a##g.RE = fmaf(mm##r, Q##rp##r, -(mm##i) * Q##rp##i); \
    a##g.IM = fmaf(mm##r, Q##rp##i,  (mm##i) * Q##rp##r);

__global__ __launch_bounds__(TPB) void qsim_kernel(
    const float* __restrict__ x,      // (B, 12)
    const float* __restrict__ w,      // (6, 12, 3)
    const float* __restrict__ hw,     // (2, 1)
    const float* __restrict__ hb,     // (2,)
    float* __restrict__ out)          // (B, 2)
{
    __shared__ f4 st[NSTATE];         // 64 KB

    const int t    = threadIdx.x;     // 8 bits
    const int lane = t & 63;
    const int e0   = blockIdx.x * 2;

    // ---- prologue: gate-constant quads into lane slots (gates 0..60 used) ----
    float gA, gB, gC, gD;
    {
        const float* wl = w + lane * 3;
        float phi = wl[0], th = wl[1], om = wl[2];
        float c, s, ca, sa, cb, sb;
        __sincosf(0.5f * th, &s, &c);
        __sincosf(0.5f * (phi + om), &sa, &ca);
        __sincosf(0.5f * (phi - om), &sb, &cb);
        gA = c * ca; gB = c * sa; gC = s * cb; gD = s * sb;
    }

    // ---- loop-invariant BYTE address bases ----
    const int ptAb  = (t ^ (t >> 4)) << 4;
    const int ptBb  = ((((t & 0xF0) << 4) | (t & 0x0F))) << 4;
    const int ptCb  = (((t << 4) ^ (t & 0x0F))) << 4;
    int gv = t << 4;                  // g^-1 = suffix parity (GF(2)-linear)
    gv ^= gv >> 1; gv ^= gv >> 2; gv ^= gv >> 4; gv ^= gv >> 8; gv &= 0xFFF;
    const int ptCSb = (gv ^ ((gv >> 4) & 0xF)) << 4;

    A2 a0, a1, a2, a3, a4, a5, a6, a7,
       a8, a9, a10, a11, a12, a13, a14, a15;

    #pragma unroll 1
    for (int k = 0; k < 4; ++k) {     // layers 2..5 (gates 12..59)
        const int gb = (k + 1) * 12;

        // ---- Pass A: state bits 11..8 (qubits 0..3) ----
        if (k == 0) {
            // init = post-layer-1 product state at i=(r<<8)|t, j = g(i):
            //   j11..9 = g4(r)>>1, j8 = r0^r1, j7 = t7^r0, j6..0 = tj bits 6..0
            const int tj = t ^ (t >> 1);
            const int t7 = (t >> 7) & 1;
            GCONST(0)  GCONST(1)  GCONST(2)  GCONST(3)
            GCONST(4)  GCONST(5)  GCONST(6)  GCONST(7)
            GCONST(8)  GCONST(9)  GCONST(10) GCONST(11)
            {   // element A
                const float* xe = x + e0 * NQ;
                float c0,s0,c1,s1,c2,s2,c3,s3,c4,s4,c5,s5;
                float c6,s6,c7,s7,c8,s8,c9,s9,c10,s10,c11,s11;
                #define EMB(q) __sincosf(0.5f * xe[q], &s##q, &c##q);
                EMB(0) EMB(1) EMB(2) EMB(3) EMB(4)  EMB(5)
                EMB(6) EMB(7) EMB(8) EMB(9) EMB(10) EMB(11)
                VQDEF(5)  WSEL(5,6)  VQDEF(6)  WSEL(6,5)
                VQDEF(7)  WSEL(7,4)  VQDEF(8)  WSEL(8,3)
                VQDEF(9)  WSEL(9,2)  VQDEF(10) WSEL(10,1)
                VQDEF(11) WSEL(11,0)
                CM(m56, w5r, w5i, w6r, w6i)   CM(m78, w7r, w7i, w8r, w8i)
                CM(m9A, w9r, w9i, w10r, w10i)
                CM(mP, m56r, m56i, m78r, m78i) CM(mQ, m9Ar, m9Ai, w11r, w11i)
                CM(mL, mPr, mPi, mQr, mQi)     // product over qubits 5..11
                VQDEF(4)
                const float w4ar = t7 ? v41r : v40r, w4ai = t7 ? v41i : v40i;
                const float w4br = t7 ? v40r : v41r, w4bi = t7 ? v40i : v41i;
                CM(Pa, mLr, mLi, w4ar, w4ai)   CM(Pb, mLr, mLi, w4br, w4bi)
                VQDEF(3)
                CM(T00, Par, Pai, v30r, v30i)  CM(T01, Par, Pai, v31r, v31i)
                CM(T10, Pbr, Pbi, v31r, v31i)  CM(T11, Pbr, Pbi, v30r, v30i)
                VQDEF(0) VQDEF(1) VQDEF(2)
                CM(H0, v00r, v00i, v10r, v10i) CM(H1, v00r, v00i, v11r, v11i)
                CM(H2, v01r, v01i, v10r, v10i) CM(H3, v01r, v01i, v11r, v11i)
                CM(Q0, H0r, H0i, v20r, v20i)   CM(Q1, H0r, H0i, v21r, v21i)
                CM(Q2, H1r, H1i, v20r, v20i)   CM(Q3, H1r, H1i, v21r, v21i)
                CM(Q4, H2r, H2i, v20r, v20i)   CM(Q5, H2r, H2i, v21r, v21i)
                CM(Q6, H3r, H3i, v20r, v20i)   CM(Q7, H3r, H3i, v21r, v21i)
                SETAMP(0,0,T00,ar,ai)  SETAMP(1,0,T10,ar,ai)
                SETAMP(2,1,T01,ar,ai)  SETAMP(3,1,T11,ar,ai)
                SETAMP(4,3,T00,ar,ai)  SETAMP(5,3,T10,ar,ai)
                SETAMP(6,2,T01,ar,ai)  SETAMP(7,2,T11,ar,ai)
                SETAMP(8,6,T00,ar,ai)  SETAMP(9,6,T10,ar,ai)
                SETAMP(10,7,T01,ar,ai) SETAMP(11,7,T11,ar,ai)
                SETAMP(12,5,T00,ar,ai) SETAMP(13,5,T10,ar,ai)
                SETAMP(14,4,T01,ar,ai) SETAMP(15,4,T11,ar,ai)
            }
            {   // element B
                const float* xe = x + (e0 + 1) * NQ;
                float c0,s0,c1,s1,c2,s2,c3,s3,c4,s4,c5,s5;
                float c6,s6,c7,s7,c8,s8,c9,s9,c10,s10,c11,s11;
                EMB(0) EMB(1) EMB(2) EMB(3) EMB(4)  EMB(5)
                EMB(6) EMB(7) EMB(8) EMB(9) EMB(10) EMB(11)
                #undef EMB
                VQDEF(5)  WSEL(5,6)  VQDEF(6)  WSEL(6,5)
                VQDEF(7)  WSEL(7,4)  VQDEF(8)  WSEL(8,3)
                VQDEF(9)  WSEL(9,2)  VQDEF(10) WSEL(10,1)
                VQDEF(11) WSEL(11,0)
                CM(m56, w5r, w5i, w6r, w6i)   CM(m78, w7r, w7i, w8r, w8i)
                CM(m9A, w9r, w9i, w10r, w10i)
                CM(mP, m56r, m56i, m78r, m78i) CM(mQ, m9Ar, m9Ai, w11r, w11i)
                CM(mL, mPr, mPi, mQr, mQi)
                VQDEF(4)
                const float w4ar = t7 ? v41r : v40r, w4ai = t7 ? v41i : v40i;
                const float w4br = t7 ? v40r : v41r, w4bi = t7 ? v40i : v41i;
                CM(Pa, mLr, mLi, w4ar, w4ai)   CM(Pb, mLr, mLi, w4br, w4bi)
                VQDEF(3)
                CM(T00, Par, Pai, v30r, v30i)  CM(T01, Par, Pai, v31r, v31i)
                CM(T10, Pbr, Pbi, v31r, v31i)  CM(T11, Pbr, Pbi, v30r, v30i)
                VQDEF(0) VQDEF(1) VQDEF(2)
                CM(H0, v00r, v00i, v10r, v10i) CM(H1, v00r, v00i, v11r, v11i)
                CM(H2, v01r, v01i, v10r, v10i) CM(H3, v01r, v01i, v11r, v11i)
                CM(Q0, H0r, H0i, v20r, v20i)   CM(Q1, H0r, H0i, v21r, v21i)
                CM(Q2, H1r, H1i, v20r, v20i)   CM(Q3, H1r, H1i, v21r, v21i)
                CM(Q4, H2r, H2i, v20r, v20i)   CM(Q5, H2r, H2i, v21r, v21i)
                CM(Q6, H3r, H3i, v20r, v20i)   CM(Q7, H3r, H3i, v21r, v21i)
                SETAMP(0,0,T00,br,bi)  SETAMP(1,0,T10,br,bi)
                SETAMP(2,1,T01,br,bi)  SETAMP(3,1,T11,br,bi)
                SETAMP(4,3,T00,br,bi)  SETAMP(5,3,T10,br,bi)
                SETAMP(6,2,T01,br,bi)  SETAMP(7,2,T11,br,bi)
                SETAMP(8,6,T00,br,bi)  SETAMP(9,6,T10,br,bi)
                SETAMP(10,7,T01,br,bi) SETAMP(11,7,T11,br,bi)
                SETAMP(12,5,T00,br,bi) SETAMP(13,5,T10,br,bi)
                SETAMP(14,4,T01,br,bi) SETAMP(15,4,T11,br,bi)
            }
        } else {
            LD16(ADRA)
        }
        // reg bit k <-> state bit 8+k <-> qubit 3-k
        GATE(3, PK0) GATE(2, PK1) GATE(1, PK2) GATE(0, PK3)
        ST16(ADRA)
        __syncthreads();

        // ---- Pass B: state bits 7..4 (qubits 4..7) ----
        LD16(ADRB)
        GATE(7, PK0) GATE(6, PK1) GATE(5, PK2) GATE(4, PK3)
        ST16(ADRB)
        __syncthreads();

        // ---- Pass C: state bits 3..0 (qubits 8..11) + Gray scatter ----
        LD16(ADRC)
        __syncthreads();              // hazard barrier hoisted: guards ONLY
                                      // reads-before-overwrites; gates run
                                      // outside the serialized window
        GATE(11, PK0) GATE(10, PK1) GATE(9, PK2) GATE(8, PK3)
        ST16(ADRCS)                   // Gray perm via g^-1 scatter
        __syncthreads();
    }

    // ---- final layer (w[5]): only gate 60 (qubit 0 = state bit 11 = reg
    //      bit 3) survives inside <Z_0>; the rest commutes out. ----
    LD16(ADRA)
    {
        const float A = RL(gA, 60), B = RL(gB, 60),
                    C = RL(gC, 60), D = RL(gD, 60);
        bf2(a0, a8,  A, B, C, D); bf2(a1, a9,  A, B, C, D);
        bf2(a2, a10, A, B, C, D); bf2(a3, a11, A, B, C, D);
        bf2(a4, a12, A, B, C, D); bf2(a5, a13, A, B, C, D);
        bf2(a6, a14, A, B, C, D); bf2(a7, a15, A, B, C, D);
    }

    // ---- <Z_0> = sum(|r<8|^2) - sum(|r>=8|^2) ----
    float za = 0.0f, zb = 0.0f;
    za += a0.ar*a0.ar + a0.ai*a0.ai;    zb += a0.br*a0.br + a0.bi*a0.bi;
    za += a1.ar*a1.ar + a1.ai*a1.ai;    zb += a1.br*a1.br + a1.bi*a1.bi;
    za += a2.ar*a2.ar + a2.ai*a2.ai;    zb += a2.br*a2.br + a2.bi*a2.bi;
    za += a3.ar*a3.ar + a3.ai*a3.ai;    zb += a3.br*a3.br + a3.bi*a3.bi;
    za += a4.ar*a4.ar + a4.ai*a4.ai;    zb += a4.br*a4.br + a4.bi*a4.bi;
    za += a5.ar*a5.ar + a5.ai*a5.ai;    zb += a5.br*a5.br + a5.bi*a5.bi;
    za += a6.ar*a6.ar + a6.ai*a6.ai;    zb += a6.br*a6.br + a6.bi*a6.bi;
    za += a7.ar*a7.ar + a7.ai*a7.ai;    zb += a7.br*a7.br + a7.bi*a7.bi;
    za -= a8.ar*a8.ar + a8.ai*a8.ai;    zb -= a8.br*a8.br + a8.bi*a8.bi;
    za -= a9.ar*a9.ar + a9.ai*a9.ai;    zb -= a9.br*a9.br + a9.bi*a9.bi;
    za -= a10.ar*a10.ar + a10.ai*a10.ai; zb -= a10.br*a10.br + a10.bi*a10.bi;
    za -= a11.ar*a11.ar + a11.ai*a11.ai; zb -= a11.br*a11.br + a11.bi*a11.bi;
    za -= a12.ar*a12.ar + a12.ai*a12.ai; zb -= a12.br*a12.br + a12.bi*a12.bi;
    za -= a13.ar*a13.ar + a13.ai*a13.ai; zb -= a13.br*a13.br + a13.bi*a13.bi;
    za -= a14.ar*a14.ar + a14.ai*a14.ai; zb -= a14.br*a14.br + a14.bi*a14.bi;
    za -= a15.ar*a15.ar + a15.ai*a15.ai; zb -= a15.br*a15.br + a15.bi*a15.bi;

    #pragma unroll
    for (int off = 32; off >= 1; off >>= 1) {
        za += __shfl_down(za, off);
        zb += __shfl_down(zb, off);
    }

    __syncthreads();                  // all final-pass reads done before reuse
    float* red = (float*)st;
    if (lane == 0) { red[t >> 6] = za; red[4 + (t >> 6)] = zb; }
    __syncthreads();

    if (t == 0) {
        float zta = red[0] + red[1] + red[2] + red[3];
        float ztb = red[4] + red[5] + red[6] + red[7];
        out[2 * e0 + 0] = zta * hw[0] + hb[0];
        out[2 * e0 + 1] = zta * hw[1] + hb[1];
        out[2 * e0 + 2] = ztb * hw[0] + hb[0];
        out[2 * e0 + 3] = ztb * hw[1] + hb[1];
    }
}

extern "C" void kernel_launch(void* const* d_in, const int* in_sizes, int n_in,
                              void* d_out, int out_size, void* d_ws, size_t ws_size,
                              hipStream_t stream) {
    const float* x  = (const float*)d_in[0];
    const float* w  = (const float*)d_in[1];
    const float* hw = (const float*)d_in[2];
    const float* hb = (const float*)d_in[3];
    float* out = (float*)d_out;
    const int B = in_sizes[0] / NQ;   // 1024
    qsim_kernel<<<B / 2, TPB, 0, stream>>>(x, w, hw, hb, out);
}